// Round 1
// 371.670 us; speedup vs baseline: 1.0025x; 1.0025x over previous
//
#include <hip/hip_runtime.h>
#include <math.h>

// Problem: B=64, T=4096, D=256
//   mids[b,d] = sum_e W[d,e] q[b,e]
//   attn[b,t] = softmax_t( tanh(k[b,t,:].mids[b,:] + bias) ), mask m applied
//               to the exp() terms.
//
// tanh in (-1,1) => exp can't overflow => max-stabilization cancels exactly.
// k streaming (256 MB fp32) is the whole cost; roofline ~38-41 us @ ~6.7 TB/s.
//
// R5: measured 372.6 us decomposes as ~320 us harness workspace re-poison
// fills (2 x 1 GiB @ ~160 us, visible as fillBufferAligned in rocprof) plus
// ~52 us of our kernels. This round fuses the mask-multiply and partial-sum
// reduction into the streaming kernel (write e*m, emit 32 partials/batch),
// dropping sum_kernel entirely: 4 launches -> 3, -2 MB HBM traffic.

#define BB 64
#define TT 4096
#define DD 256
#define TBLKS 32
#define RPB 128               // rows per block (t-dim)
#define CROWS 16              // rows per LDS chunk (16 KB)
#define NCH (RPB / CROWS)     // 8 chunks
#define GB 8
#define CHUNK (TT / GB)       // 512

// ---- DPP 16-lane full sum tree (all lanes end with the group sum) ----
template<int CTRL>
__device__ __forceinline__ float dpp_add(float x) {
    int xi = __builtin_bit_cast(int, x);
    int yi = __builtin_amdgcn_update_dpp(0, xi, CTRL, 0xF, 0xF, true);
    return x + __builtin_bit_cast(float, yi);
}
__device__ __forceinline__ float row16_sum(float p) {
    p = dpp_add<0xB1>(p);     // xor 1
    p = dpp_add<0x4E>(p);     // xor 2
    p = dpp_add<0x141>(p);    // row_half_mirror
    p = dpp_add<0x140>(p);    // row_mirror
    return p;
}

// tanh(x) = 1 - 2/(1 + e^{2x}); exact at +-inf.
__device__ __forceinline__ float fast_tanh(float x) {
    float e = __expf(2.0f * x);
    return 1.0f - 2.0f * __builtin_amdgcn_rcpf(1.0f + e);
}

// async global->LDS: one instruction moves 64 lanes x 16 B = one 1 KB row.
// LDS dest is wave-uniform base + lane*16 (hardware scatter).
__device__ __forceinline__ void async_row1k(const float* g, float* lds) {
    __builtin_amdgcn_global_load_lds(
        (const __attribute__((address_space(1))) void*)g,
        (__attribute__((address_space(3))) void*)lds,
        16, 0, 0);
}

// ---------------- K1: mids = W @ q^T ----------------
// grid (B, 16); 4 waves; each 16-lane group computes one d.
__global__ __launch_bounds__(256) void mids_kernel(const float* __restrict__ q,
                                                   const float* __restrict__ W,
                                                   float* __restrict__ mids) {
    const int b    = blockIdx.x;
    const int seg  = blockIdx.y;
    const int lane = threadIdx.x & 63;
    const int wave = threadIdx.x >> 6;
    const int grp  = lane >> 4;
    const int l16  = lane & 15;

    const float* qb = q + (size_t)b * DD + l16 * 4;
    const float4 qf0 = *(const float4*)(qb + 0);
    const float4 qf1 = *(const float4*)(qb + 64);
    const float4 qf2 = *(const float4*)(qb + 128);
    const float4 qf3 = *(const float4*)(qb + 192);

    const int d = seg * 16 + wave * 4 + grp;
    const float* wr = W + (size_t)d * DD + l16 * 4;
    const float4 w0 = *(const float4*)(wr + 0);
    const float4 w1 = *(const float4*)(wr + 64);
    const float4 w2 = *(const float4*)(wr + 128);
    const float4 w3 = *(const float4*)(wr + 192);
    float p = w0.x*qf0.x + w0.y*qf0.y + w0.z*qf0.z + w0.w*qf0.w;
    p += w1.x*qf1.x + w1.y*qf1.y + w1.z*qf1.z + w1.w*qf1.w;
    p += w2.x*qf2.x + w2.y*qf2.y + w2.z*qf2.z + w2.w*qf2.w;
    p += w3.x*qf3.x + w3.y*qf3.y + w3.z*qf3.z + w3.w*qf3.w;
    p = row16_sum(p);
    if (l16 == 0) mids[b * DD + d] = p;
}

// ---------------- K2: out[b,t] = m[b,t]*exp(tanh(k.mids + bias)) ----------
// grid (B, TBLKS); block streams 128 rows (128 KB) of k through LDS in
// 16-row chunks, double-buffered. Wave w stages rows w*4..w*4+3 of each
// chunk; 16-lane group g computes row g of the chunk. The mask multiply
// and the per-block partial sum of e*m are fused here (R5): out holds
// e*m, bsum[b*TBLKS+tb] holds this block's partial of sum_t e*m.
__global__ __launch_bounds__(256) void stream_kernel(const float* __restrict__ k,
                                                     const float* __restrict__ mids,
                                                     const float* __restrict__ bias,
                                                     const float* __restrict__ m,
                                                     float* __restrict__ out,
                                                     float* __restrict__ bsum) {
    __shared__ float buf[2][CROWS * DD];   // 2 x 16 KB
    __shared__ float wsum[16];
    const int b     = blockIdx.x;
    const int tb    = blockIdx.y;
    const int tid   = threadIdx.x;
    const int lane  = tid & 63;
    const int wave  = tid >> 6;
    const int l16   = lane & 15;
    const int grp16 = tid >> 4;            // 0..15: my row within the chunk
    const float bv  = bias[0];

    const float* mb = mids + (size_t)b * DD + l16 * 4;
    const float4 mf0 = *(const float4*)(mb + 0);
    const float4 mf1 = *(const float4*)(mb + 64);
    const float4 mf2 = *(const float4*)(mb + 128);
    const float4 mf3 = *(const float4*)(mb + 192);

    const int t0 = tb * RPB;
    const float* kb   = k + ((size_t)b * TT + t0) * DD;
    const float* mrow = m + (size_t)b * TT + t0;
    float* orow = out + (size_t)b * TT + t0;

    float gsum = 0.0f;                     // valid on l16==0 lanes

    // prologue: stage chunk 0
    {
        const float* src = kb + (size_t)(wave * 4) * DD + lane * 4;
        float* dst = &buf[0][(wave * 4) * DD];
        #pragma unroll
        for (int j = 0; j < 4; ++j) async_row1k(src + j * DD, dst + j * DD);
    }

    for (int c = 0; c < NCH; ++c) {
        if (c + 1 < NCH) {   // stage next chunk into the other buffer
            const float* src = kb + (size_t)((c + 1) * CROWS + wave * 4) * DD + lane * 4;
            float* dst = &buf[(c + 1) & 1][(wave * 4) * DD];
            #pragma unroll
            for (int j = 0; j < 4; ++j) async_row1k(src + j * DD, dst + j * DD);
        }
        __syncthreads();     // vmcnt drain + barrier: chunk c visible

        const float* row = &buf[c & 1][grp16 * DD + l16 * 4];
        const float4 r0 = *(const float4*)(row + 0);
        const float4 r1 = *(const float4*)(row + 64);
        const float4 r2 = *(const float4*)(row + 128);
        const float4 r3 = *(const float4*)(row + 192);
        float p = r0.x*mf0.x + r0.y*mf0.y + r0.z*mf0.z + r0.w*mf0.w;
        p += r1.x*mf1.x + r1.y*mf1.y + r1.z*mf1.z + r1.w*mf1.w;
        p += r2.x*mf2.x + r2.y*mf2.y + r2.z*mf2.z + r2.w*mf2.w;
        p += r3.x*mf3.x + r3.y*mf3.y + r3.z*mf3.z + r3.w*mf3.w;
        p = row16_sum(p);                      // group-uniform dot
        const float e = __expf(fast_tanh(p + bv));
        if (l16 == 0) {
            const int r = c * CROWS + grp16;
            const float val = e * mrow[r];     // fused mask multiply
            orow[r] = val;
            gsum += val;
        }

        __syncthreads();     // protect buf[c&1] before it is restaged
    }

    // block partial sum: 16 groups -> 1 value
    if (l16 == 0) wsum[grp16] = gsum;
    __syncthreads();
    if (tid == 0) {
        float s = 0.0f;
        #pragma unroll
        for (int i = 0; i < 16; ++i) s += wsum[i];
        bsum[b * TBLKS + tb] = s;
    }
}

// ---------------- K3: out = out / sum ----------------
__global__ __launch_bounds__(256) void finish_kernel(const float* __restrict__ bsum,
                                                     float* __restrict__ out) {
    const int b   = blockIdx.x;
    const int g   = blockIdx.y;
    const int tid = threadIdx.x;
    float s = 0.0f;
    #pragma unroll
    for (int i = 0; i < TBLKS; ++i) s += bsum[b * TBLKS + i];  // uniform scalar loads
    const float inv = 1.0f / s;
    const int idx = b * TT + g * CHUNK + tid * 2;
    float2 v = *(const float2*)(out + idx);
    v.x *= inv; v.y *= inv;
    *(float2*)(out + idx) = v;
}

extern "C" void kernel_launch(void* const* d_in, const int* in_sizes, int n_in,
                              void* d_out, int out_size, void* d_ws, size_t ws_size,
                              hipStream_t stream) {
    const float* q    = (const float*)d_in[0];   // [B, D]
    const float* k    = (const float*)d_in[1];   // [B, T, D]
    const float* m    = (const float*)d_in[2];   // [B, T]
    const float* W    = (const float*)d_in[3];   // [D, D]
    const float* bias = (const float*)d_in[4];   // [1]
    float* out = (float*)d_out;                  // [B, T]

    float* ws   = (float*)d_ws;
    float* mids = ws;                            // B*D     = 16384 floats
    float* bsum = mids + BB * DD;                // B*TBLKS = 2048 floats

    mids_kernel<<<dim3(BB, 16), 256, 0, stream>>>(q, W, mids);
    stream_kernel<<<dim3(BB, TBLKS), 256, 0, stream>>>(k, mids, bias, m, out, bsum);
    finish_kernel<<<dim3(BB, GB), 256, 0, stream>>>(bsum, out);
}